// Round 6
// baseline (10.839 us; speedup 1.0000x reference)
//
#include <hip/hip_runtime.h>

// CRF score: out = (sum_m emissions[b,s,tag] + sum_pairs transitions[t0,t1]) / sum(m)
// B=512, S=512, T=128 hardcoded. 4 elems/thread (int4 loads), 256 blocks x 256
// threads (one block per CU). SINGLE dispatch, relaxed agent-scope (sc1)
// flag barrier -> no wbl2/inv cache maintenance. Poison-safe: flags written 1
// every call, reset to 0 by block 0.

constexpr int S = 512;
constexpr int TOTAL = 512 * 512;          // B*S
constexpr int EPT = 4;                    // elements per thread
constexpr int NBLK = TOTAL / (256 * EPT); // 256

__global__ __launch_bounds__(256) void crf_fused_kernel(
        const float* __restrict__ emissions,
        const int* __restrict__ tags,
        const int* __restrict__ mask,
        const float* __restrict__ transitions,
        double* __restrict__ part_val,
        unsigned int* __restrict__ part_cnt,
        unsigned int* __restrict__ flags,
        float* __restrict__ out) {
    int gid = blockIdx.x * 256 + threadIdx.x;     // 0 .. TOTAL/4-1
    int idx = gid << 2;                           // first of 4 consecutive elements

    int4 tg = ((const int4*)tags)[gid];
    int4 mk = ((const int4*)mask)[gid];

    float contrib = 0.0f;
    unsigned int cnt = 0;

    int tga[4] = {tg.x, tg.y, tg.z, tg.w};
    int mka[4] = {mk.x, mk.y, mk.z, mk.w};

    // emissions gathers: offset = (idx+k)*128 + tag
    #pragma unroll
    for (int k = 0; k < 4; ++k) {
        if (mka[k]) {
            contrib += emissions[(((size_t)idx + k) << 7) + (size_t)tga[k]];
            ++cnt;
        }
    }

    // in-thread pairs (idx+k, idx+k+1), k=0..2: idx%4==0 and S%4==0 -> never
    // cross a sequence boundary
    #pragma unroll
    for (int k = 0; k < 3; ++k) {
        if (mka[k] & mka[k + 1])
            contrib += transitions[(tga[k] << 7) + tga[k + 1]];
    }

    // cross-thread pair (idx+3, idx+4): skip when idx+3 is last in sequence
    if (((idx + 3) & (S - 1)) != S - 1 && mka[3]) {
        if (mask[idx + 4]) contrib += transitions[(tga[3] << 7) + tags[idx + 4]];
    }

    // wave(64) reduction
    double val = (double)contrib;
    #pragma unroll
    for (int off = 32; off > 0; off >>= 1) {
        val += __shfl_down(val, off, 64);
        cnt += __shfl_down(cnt, off, 64);
    }

    __shared__ double s_val[4];
    __shared__ unsigned int s_cnt[4];
    int wave = threadIdx.x >> 6;
    int lane = threadIdx.x & 63;
    if (lane == 0) { s_val[wave] = val; s_cnt[wave] = cnt; }
    __syncthreads();

    if (threadIdx.x == 0) {
        double bv = s_val[0] + s_val[1] + s_val[2] + s_val[3];
        unsigned int bc = s_cnt[0] + s_cnt[1] + s_cnt[2] + s_cnt[3];
        // sc1 stores: straight to the coherence point (IF cache)
        __hip_atomic_store(&part_val[blockIdx.x], bv, __ATOMIC_RELAXED,
                           __HIP_MEMORY_SCOPE_AGENT);
        __hip_atomic_store(&part_cnt[blockIdx.x], bc, __ATOMIC_RELAXED,
                           __HIP_MEMORY_SCOPE_AGENT);
        // order: partials committed at coherence point before the flag
        asm volatile("s_waitcnt vmcnt(0)" ::: "memory");
        __hip_atomic_store(&flags[blockIdx.x], 1u, __ATOMIC_RELAXED,
                           __HIP_MEMORY_SCOPE_AGENT);
    }

    // ---- finalizer: block 0 waits for all partials, reduces, writes out ----
    if (blockIdx.x == 0) {
        __syncthreads();   // phase-1 shared reads done before reuse
        int t = threadIdx.x;
        double v = 0.0;
        unsigned int c = 0;
        // NBLK == 256: one flag per thread
        while (__hip_atomic_load(&flags[t], __ATOMIC_RELAXED,
                                 __HIP_MEMORY_SCOPE_AGENT) != 1u) { }
        v = __hip_atomic_load(&part_val[t], __ATOMIC_RELAXED,
                              __HIP_MEMORY_SCOPE_AGENT);
        c = __hip_atomic_load(&part_cnt[t], __ATOMIC_RELAXED,
                              __HIP_MEMORY_SCOPE_AGENT);
        // reset for next graph replay (kernel-end ordering makes this safe)
        __hip_atomic_store(&flags[t], 0u, __ATOMIC_RELAXED,
                           __HIP_MEMORY_SCOPE_AGENT);

        #pragma unroll
        for (int off = 32; off > 0; off >>= 1) {
            v += __shfl_down(v, off, 64);
            c += __shfl_down(c, off, 64);
        }
        __shared__ double f_val[4];
        __shared__ unsigned int f_cnt[4];
        if (lane == 0) { f_val[wave] = v; f_cnt[wave] = c; }
        __syncthreads();
        if (t == 0) {
            double vv = f_val[0] + f_val[1] + f_val[2] + f_val[3];
            unsigned int cc = f_cnt[0] + f_cnt[1] + f_cnt[2] + f_cnt[3];
            out[0] = (float)(vv / (double)cc);
        }
    }
}

extern "C" void kernel_launch(void* const* d_in, const int* in_sizes, int n_in,
                              void* d_out, int out_size, void* d_ws, size_t ws_size,
                              hipStream_t stream) {
    const float* emissions   = (const float*)d_in[0];
    const int*   tags        = (const int*)d_in[1];
    const int*   mask        = (const int*)d_in[2];
    const float* transitions = (const float*)d_in[3];
    float* out = (float*)d_out;

    double*       part_val = (double*)d_ws;
    unsigned int* part_cnt = (unsigned int*)((char*)d_ws + NBLK * sizeof(double));
    unsigned int* flags    = (unsigned int*)((char*)d_ws + NBLK * (sizeof(double) + sizeof(unsigned int)));

    crf_fused_kernel<<<NBLK, 256, 0, stream>>>(emissions, tags, mask, transitions,
                                               part_val, part_cnt, flags, out);
}

// Round 7
// 10.001 us; speedup vs baseline: 1.0838x; 1.0838x over previous
//
#include <hip/hip_runtime.h>

// CRF score: out = (sum_m emissions[b,s,tag] + sum_pairs transitions[t0,t1]) / sum(m)
// B=512, S=512, T=128 hardcoded. 1 elem/thread, 512 blocks x 512 threads
// (4096 waves = 4/SIMD for max latency hiding). Neighbor tag/mask via
// __shfl_down (lane 63 reloads from global). SINGLE dispatch, relaxed
// agent-scope (sc1) flag barrier -> no wbl2/inv cache maintenance.
// Poison-safe: flags written 1 every call, reset to 0 by block 0.

constexpr int S = 512;
constexpr int TOTAL = 512 * 512;          // B*S
constexpr int BLOCK = 512;
constexpr int NBLK = TOTAL / BLOCK;       // 512
constexpr int NWAVE = BLOCK / 64;         // 8

__global__ __launch_bounds__(512) void crf_fused_kernel(
        const float* __restrict__ emissions,
        const int* __restrict__ tags,
        const int* __restrict__ mask,
        const float* __restrict__ transitions,
        double* __restrict__ part_val,
        unsigned int* __restrict__ part_cnt,
        unsigned int* __restrict__ flags,
        float* __restrict__ out) {
    int idx = blockIdx.x * BLOCK + threadIdx.x;   // 0 .. TOTAL-1
    int lane = threadIdx.x & 63;
    int wave = threadIdx.x >> 6;

    int t = tags[idx];
    int m = mask[idx];

    float contrib = 0.0f;
    unsigned int cnt = 0;

    // emission gather: offset = idx*128 + tag
    if (m) {
        contrib += emissions[((size_t)idx << 7) + (size_t)t];
        ++cnt;
    }

    // pair (idx, idx+1): neighbor via shuffle; lane 63 reloads from global
    int s0 = idx & (S - 1);
    int t1 = __shfl_down(t, 1, 64);
    int m1 = __shfl_down(m, 1, 64);
    if (s0 != S - 1) {
        if (lane == 63) {            // idx+1 exists since s0 != S-1
            t1 = tags[idx + 1];
            m1 = mask[idx + 1];
        }
        if (m & m1) contrib += transitions[(t << 7) + t1];
    }

    // wave(64) reduction
    double val = (double)contrib;
    #pragma unroll
    for (int off = 32; off > 0; off >>= 1) {
        val += __shfl_down(val, off, 64);
        cnt += __shfl_down(cnt, off, 64);
    }

    __shared__ double s_val[NWAVE];
    __shared__ unsigned int s_cnt[NWAVE];
    if (lane == 0) { s_val[wave] = val; s_cnt[wave] = cnt; }
    __syncthreads();

    if (threadIdx.x == 0) {
        double bv = 0.0;
        unsigned int bc = 0;
        #pragma unroll
        for (int w = 0; w < NWAVE; ++w) { bv += s_val[w]; bc += s_cnt[w]; }
        // sc1 stores: straight to the coherence point
        __hip_atomic_store(&part_val[blockIdx.x], bv, __ATOMIC_RELAXED,
                           __HIP_MEMORY_SCOPE_AGENT);
        __hip_atomic_store(&part_cnt[blockIdx.x], bc, __ATOMIC_RELAXED,
                           __HIP_MEMORY_SCOPE_AGENT);
        // order: partials committed at coherence point before the flag
        asm volatile("s_waitcnt vmcnt(0)" ::: "memory");
        __hip_atomic_store(&flags[blockIdx.x], 1u, __ATOMIC_RELAXED,
                           __HIP_MEMORY_SCOPE_AGENT);
    }

    // ---- finalizer: block 0 waits for all partials, reduces, writes out ----
    if (blockIdx.x == 0) {
        __syncthreads();   // phase-1 shared reads done before reuse
        int tt = threadIdx.x;
        // NBLK == BLOCK: one flag per thread
        while (__hip_atomic_load(&flags[tt], __ATOMIC_RELAXED,
                                 __HIP_MEMORY_SCOPE_AGENT) != 1u) { }
        double v = __hip_atomic_load(&part_val[tt], __ATOMIC_RELAXED,
                                     __HIP_MEMORY_SCOPE_AGENT);
        unsigned int c = __hip_atomic_load(&part_cnt[tt], __ATOMIC_RELAXED,
                                           __HIP_MEMORY_SCOPE_AGENT);
        // reset for next graph replay
        __hip_atomic_store(&flags[tt], 0u, __ATOMIC_RELAXED,
                           __HIP_MEMORY_SCOPE_AGENT);

        #pragma unroll
        for (int off = 32; off > 0; off >>= 1) {
            v += __shfl_down(v, off, 64);
            c += __shfl_down(c, off, 64);
        }
        __shared__ double f_val[NWAVE];
        __shared__ unsigned int f_cnt[NWAVE];
        if (lane == 0) { f_val[wave] = v; f_cnt[wave] = c; }
        __syncthreads();
        if (tt == 0) {
            double vv = 0.0;
            unsigned int cc = 0;
            #pragma unroll
            for (int w = 0; w < NWAVE; ++w) { vv += f_val[w]; cc += f_cnt[w]; }
            out[0] = (float)(vv / (double)cc);
        }
    }
}

extern "C" void kernel_launch(void* const* d_in, const int* in_sizes, int n_in,
                              void* d_out, int out_size, void* d_ws, size_t ws_size,
                              hipStream_t stream) {
    const float* emissions   = (const float*)d_in[0];
    const int*   tags        = (const int*)d_in[1];
    const int*   mask        = (const int*)d_in[2];
    const float* transitions = (const float*)d_in[3];
    float* out = (float*)d_out;

    double*       part_val = (double*)d_ws;
    unsigned int* part_cnt = (unsigned int*)((char*)d_ws + NBLK * sizeof(double));
    unsigned int* flags    = (unsigned int*)((char*)d_ws + NBLK * (sizeof(double) + sizeof(unsigned int)));

    crf_fused_kernel<<<NBLK, BLOCK, 0, stream>>>(emissions, tags, mask, transitions,
                                                 part_val, part_cnt, flags, out);
}